// Round 1
// baseline (2121.066 us; speedup 1.0000x reference)
//
#include <hip/hip_runtime.h>
#include <stdint.h>

#define NGO   40000
#define MP    40064          // 313 * 128
#define NEDGE 640000

typedef __bf16 bf16x8 __attribute__((ext_vector_type(8)));
typedef float  f32x4  __attribute__((ext_vector_type(4)));

__device__ __forceinline__ unsigned short f2bf(float f) {
  unsigned x = __float_as_uint(f);
  x += 0x7fffu + ((x >> 16) & 1u);           // RNE
  return (unsigned short)(x >> 16);
}

// ---------------------------------------------------------------------------
// f32 -> bf16 cast with trailing zero pad (pad rows of padded buffers)
__global__ void castpad_kernel(const float* __restrict__ src,
                               unsigned short* __restrict__ dst,
                               long long nsrc, long long ndst) {
  long long i = (long long)blockIdx.x * blockDim.x + threadIdx.x;
  if (i >= ndst) return;
  dst[i] = (i < nsrc) ? f2bf(src[i]) : (unsigned short)0;
}

// transpose + cast: src [R][C] f32 -> dst [C][R] bf16
__global__ __launch_bounds__(256) void tcast_kernel(const float* __restrict__ src,
                                                    unsigned short* __restrict__ dst,
                                                    int R, int C) {
  __shared__ float tile[32][33];
  int bc = blockIdx.x * 32, br = blockIdx.y * 32;
  int tx = threadIdx.x, ty = threadIdx.y;  // (32, 8)
#pragma unroll
  for (int j = 0; j < 4; j++) {
    int r = br + ty + j * 8, c = bc + tx;
    if (r < R && c < C) tile[ty + j * 8][tx] = src[(size_t)r * C + c];
  }
  __syncthreads();
#pragma unroll
  for (int j = 0; j < 4; j++) {
    int c = bc + ty + j * 8, r = br + tx;
    if (r < R && c < C) dst[(size_t)c * R + r] = f2bf(tile[tx][ty + j * 8]);
  }
}

// ---------------------------------------------------------------------------
// CSR build
__global__ void hist_kernel(const int* __restrict__ row, int* __restrict__ counts, int n) {
  int i = blockIdx.x * blockDim.x + threadIdx.x;
  if (i < n) atomicAdd(&counts[row[i]], 1);
}

__global__ __launch_bounds__(1024) void scan_kernel(const int* __restrict__ counts,
                                                    int* __restrict__ row_start, int n) {
  __shared__ int sh[1024];
  __shared__ int carry_s;
  const int t = threadIdx.x;
  if (t == 0) carry_s = 0;
  __syncthreads();
  for (int base = 0; base < n; base += 1024) {
    int v = (base + t < n) ? counts[base + t] : 0;
    sh[t] = v;
    __syncthreads();
    for (int o = 1; o < 1024; o <<= 1) {
      int x = (t >= o) ? sh[t - o] : 0;
      __syncthreads();
      sh[t] += x;
      __syncthreads();
    }
    int carry = carry_s;
    if (base + t < n) row_start[base + t] = carry + sh[t] - v;  // exclusive
    __syncthreads();
    if (t == 0) carry_s = carry + sh[1023];
    __syncthreads();
  }
  if (t == 0) row_start[n] = carry_s;
}

__global__ void scatter_kernel(const int* __restrict__ row, const int* __restrict__ col,
                               const float* __restrict__ val, int* __restrict__ fill,
                               int* __restrict__ ocol, float* __restrict__ oval, int n) {
  int i = blockIdx.x * blockDim.x + threadIdx.x;
  if (i < n) {
    int r = row[i];
    int p = atomicAdd(&fill[r], 1);
    ocol[p] = col[i];
    oval[p] = val[i];
  }
}

// ---------------------------------------------------------------------------
// SpMM over CSR: one block (256 thr) per output row, 512 cols (2 per thread,
// packed as one u32 = 2 bf16). X is bf16 [*, 512] (u32-packed: 256/row).
// FUSE: += bias, relu, store f32 to Of AND bf16 to Ob; else bf16 only.
template <bool FUSE>
__global__ __launch_bounds__(256) void spmm_csr_kernel(
    const int* __restrict__ rs, const int* __restrict__ cols,
    const float* __restrict__ vals, const unsigned* __restrict__ Xu,
    unsigned* __restrict__ Ob, int ob_stride, int ob_off,
    float* __restrict__ Of, const float* __restrict__ bias) {
  const int row = blockIdx.x;
  const int t = threadIdx.x;
  const int s = rs[row], e = rs[row + 1];
  float a0 = 0.f, a1 = 0.f;
  for (int i = s; i < e; i++) {
    int c = cols[i];
    float v = vals[i];
    unsigned u = Xu[(size_t)c * 256 + t];
    a0 = fmaf(v, __uint_as_float((u & 0xffffu) << 16), a0);
    a1 = fmaf(v, __uint_as_float(u & 0xffff0000u), a1);
  }
  if (FUSE) {
    a0 += bias[2 * t];
    a1 += bias[2 * t + 1];
    a0 = fmaxf(a0, 0.f);
    a1 = fmaxf(a1, 0.f);
    Of[(size_t)row * 512 + 2 * t] = a0;
    Of[(size_t)row * 512 + 2 * t + 1] = a1;
  }
  Ob[(size_t)row * ob_stride + ob_off + t] = ((unsigned)f2bf(a1) << 16) | (unsigned)f2bf(a0);
}

// ---------------------------------------------------------------------------
// NT bf16 GEMM: C[M,N] = A[M,K] * Bt[N,K]^T  (m97-style: 128x128 tile, BK=32,
// global_load_lds width 16, mfma_f32_16x16x32_bf16). M,N multiples of 128,
// K multiple of 32. f32 store guarded by (mf, nf); bf16 store unguarded.
template <bool RELU, bool SIG, bool BIAS, bool SF32, bool SB16>
__global__ __launch_bounds__(256) void gemm_nt(
    const unsigned short* __restrict__ A, const unsigned short* __restrict__ Bt,
    const float* __restrict__ bias,
    float* __restrict__ Cf, int ldf, int mf, int nf,
    unsigned short* __restrict__ Cb, int ldb, int cb0, int K) {
  __shared__ bf16x8 sA[512];  // 128 rows x 32 bf16
  __shared__ bf16x8 sB[512];

  const int t = threadIdx.x;
  const int lane = t & 63;
  const int w = t >> 6;
  const int bn = blockIdx.x * 128;
  const int bm = blockIdx.y * 128;

  // staging: chunk c covers LDS bytes [16c,16c+16); row = c>>2, col = (c&3)*8 bf16
  const int c0 = w * 64 + lane;
  const int c1 = c0 + 256;
  const unsigned short* gA0 = A + (size_t)(bm + (c0 >> 2)) * K + (c0 & 3) * 8;
  const unsigned short* gA1 = A + (size_t)(bm + (c1 >> 2)) * K + (c1 & 3) * 8;
  const unsigned short* gB0 = Bt + (size_t)(bn + (c0 >> 2)) * K + (c0 & 3) * 8;
  const unsigned short* gB1 = Bt + (size_t)(bn + (c1 >> 2)) * K + (c1 & 3) * 8;
  char* lA0 = (char*)sA + (size_t)w * 1024;
  char* lA1 = (char*)sA + (size_t)(4 + w) * 1024;
  char* lB0 = (char*)sB + (size_t)w * 1024;
  char* lB1 = (char*)sB + (size_t)(4 + w) * 1024;

  const int lr = lane & 15;
  const int q = lane >> 4;          // quad
  const int wr = (w >> 1) * 64;
  const int wc = (w & 1) * 64;

  f32x4 acc[4][4] = {};

  for (int k0 = 0; k0 < K; k0 += 32) {
    __builtin_amdgcn_global_load_lds(
        (const __attribute__((address_space(1))) void*)(gA0 + k0),
        (__attribute__((address_space(3))) void*)lA0, 16, 0, 0);
    __builtin_amdgcn_global_load_lds(
        (const __attribute__((address_space(1))) void*)(gA1 + k0),
        (__attribute__((address_space(3))) void*)lA1, 16, 0, 0);
    __builtin_amdgcn_global_load_lds(
        (const __attribute__((address_space(1))) void*)(gB0 + k0),
        (__attribute__((address_space(3))) void*)lB0, 16, 0, 0);
    __builtin_amdgcn_global_load_lds(
        (const __attribute__((address_space(1))) void*)(gB1 + k0),
        (__attribute__((address_space(3))) void*)lB1, 16, 0, 0);
    __syncthreads();

    bf16x8 af[4], bfr[4];
#pragma unroll
    for (int i = 0; i < 4; i++) af[i] = sA[(wr + i * 16 + lr) * 4 + q];
#pragma unroll
    for (int j = 0; j < 4; j++) bfr[j] = sB[(wc + j * 16 + lr) * 4 + q];
#pragma unroll
    for (int i = 0; i < 4; i++)
#pragma unroll
      for (int j = 0; j < 4; j++)
        acc[i][j] = __builtin_amdgcn_mfma_f32_16x16x32_bf16(af[i], bfr[j], acc[i][j], 0, 0, 0);
    __syncthreads();
  }

  // epilogue: C/D layout col = lane&15, row = quad*4 + r  [verified m89/m91]
  const int r0 = q * 4;
#pragma unroll
  for (int i = 0; i < 4; i++) {
#pragma unroll
    for (int j = 0; j < 4; j++) {
      const int col = bn + wc + j * 16 + lr;
      const float bv = BIAS ? bias[col] : 0.f;
#pragma unroll
      for (int r = 0; r < 4; r++) {
        const int row = bm + wr + i * 16 + r0 + r;
        float v = acc[i][j][r] + bv;
        if (RELU) v = fmaxf(v, 0.f);
        if (SIG) v = 1.f / (1.f + __expf(-v));
        if (SB16) Cb[(size_t)row * ldb + cb0 + col] = f2bf(v);
        if (SF32) {
          if (row < mf && col < nf) Cf[(size_t)row * ldf + col] = v;
        }
      }
    }
  }
}

// ---------------------------------------------------------------------------
extern "C" void kernel_launch(void* const* d_in, const int* in_sizes, int n_in,
                              void* d_out, int out_size, void* d_ws, size_t ws_size,
                              hipStream_t stream) {
  const float* seq    = (const float*)d_in[0];
  const float* go     = (const float*)d_in[1];
  const int*   erow   = (const int*)d_in[2];
  const int*   ecol   = (const int*)d_in[3];
  const float* evalp  = (const float*)d_in[4];
  const float* mlp_w1 = (const float*)d_in[5];
  const float* mlp_b1 = (const float*)d_in[6];
  const float* mlp_w2 = (const float*)d_in[7];
  const float* mlp_b2 = (const float*)d_in[8];
  const float* gc1_w  = (const float*)d_in[9];
  const float* gc1_b  = (const float*)d_in[10];
  const float* gc2_w  = (const float*)d_in[11];
  const float* gc2_b  = (const float*)d_in[12];
  const float* se_w1  = (const float*)d_in[13];
  const float* se_b1  = (const float*)d_in[14];
  const float* se_w2  = (const float*)d_in[15];
  const float* se_b2  = (const float*)d_in[16];
  const int n_edges = in_sizes[2];

  float* out_f = (float*)d_out;
  float* out_hsem = out_f;                        // [40000,512]
  float* out_hstr = out_f + (size_t)NGO * 512;    // [40000,512]
  float* out_pred = out_f + (size_t)NGO * 1024;   // [4096,40000]

  char* ws = (char*)d_ws;
  size_t off = 0;
  auto alloc = [&](size_t bytes) -> char* {
    char* p = ws + off;
    off += (bytes + 255) & ~(size_t)255;
    return p;
  };
  unsigned short* w1t   = (unsigned short*)alloc((size_t)1024 * 512 * 2);
  unsigned short* w2t   = (unsigned short*)alloc((size_t)512 * 1024 * 2);
  unsigned short* gc1t  = (unsigned short*)alloc((size_t)1024 * 512 * 2);
  unsigned short* gc2t  = (unsigned short*)alloc((size_t)512 * 1024 * 2);
  unsigned short* se1t  = (unsigned short*)alloc((size_t)1024 * 1280 * 2);
  unsigned short* se2t  = (unsigned short*)alloc((size_t)1024 * 1024 * 2);
  unsigned short* slot2 = (unsigned short*)alloc((size_t)MP * 512 * 2);   // GO16 -> xw16
  unsigned short* slot1 = (unsigned short*)alloc((size_t)MP * 1024 * 2);  // h1 -> x16
  unsigned short* gocat = (unsigned short*)alloc((size_t)MP * 1024 * 2);  // [hsem|hstr] bf16
  unsigned short* ax16  = (unsigned short*)alloc((size_t)MP * 512 * 2);   // spmm1 out
  unsigned short* seq16 = (unsigned short*)alloc((size_t)4096 * 1280 * 2);
  unsigned short* s1b   = (unsigned short*)alloc((size_t)4096 * 1024 * 2);
  unsigned short* so16  = (unsigned short*)alloc((size_t)4096 * 1024 * 2);
  int*   counts    = (int*)alloc((size_t)NGO * 4);
  int*   row_start = (int*)alloc((size_t)(NGO + 1) * 4);
  int*   fill      = (int*)alloc((size_t)NGO * 4);
  int*   csr_col   = (int*)alloc((size_t)NEDGE * 4);
  float* csr_val   = (float*)alloc((size_t)NEDGE * 4);

  unsigned short* GO16 = slot2;
  unsigned short* xw16 = slot2;
  unsigned short* h1   = slot1;
  unsigned short* x16  = slot1;

  // --- init ---
  hipMemsetAsync(counts, 0, (size_t)NGO * 4, stream);
  hipMemsetAsync(gocat + (size_t)NGO * 1024, 0, (size_t)(MP - NGO) * 1024 * 2, stream);

  // --- weight transpose+cast ---
  dim3 tb(32, 8);
  tcast_kernel<<<dim3(1024 / 32, 512 / 32), tb, 0, stream>>>(mlp_w1, w1t, 512, 1024);
  tcast_kernel<<<dim3(512 / 32, 1024 / 32), tb, 0, stream>>>(mlp_w2, w2t, 1024, 512);
  tcast_kernel<<<dim3(1024 / 32, 512 / 32), tb, 0, stream>>>(gc1_w, gc1t, 512, 1024);
  tcast_kernel<<<dim3(512 / 32, 1024 / 32), tb, 0, stream>>>(gc2_w, gc2t, 1024, 512);
  tcast_kernel<<<dim3(1024 / 32, 1280 / 32), tb, 0, stream>>>(se_w1, se1t, 1280, 1024);
  tcast_kernel<<<dim3(1024 / 32, 1024 / 32), tb, 0, stream>>>(se_w2, se2t, 1024, 1024);

  // --- activation casts ---
  {
    long long nsrc = (long long)NGO * 512, ndst = (long long)MP * 512;
    castpad_kernel<<<(int)((ndst + 255) / 256), 256, 0, stream>>>(go, GO16, nsrc, ndst);
    long long ns2 = (long long)4096 * 1280;
    castpad_kernel<<<(int)((ns2 + 255) / 256), 256, 0, stream>>>(seq, seq16, ns2, ns2);
  }

  // --- CSR build ---
  hist_kernel<<<(n_edges + 255) / 256, 256, 0, stream>>>(erow, counts, n_edges);
  scan_kernel<<<1, 1024, 0, stream>>>(counts, row_start, NGO);
  hipMemcpyAsync(fill, row_start, (size_t)NGO * 4, hipMemcpyDeviceToDevice, stream);
  scatter_kernel<<<(n_edges + 255) / 256, 256, 0, stream>>>(erow, ecol, evalp, fill,
                                                            csr_col, csr_val, n_edges);

  // --- semantic branch ---
  // G1: h1 = relu(GO16 @ mlp_w1 + b1)   [MP,1024] K=512
  gemm_nt<true, false, true, false, true><<<dim3(8, MP / 128), 256, 0, stream>>>(
      GO16, w1t, mlp_b1, nullptr, 0, 0, 0, h1, 1024, 0, 512);
  // G2: h_sem = h1 @ mlp_w2 + b2  -> f32 d_out + bf16 gocat[:,0:512]  K=1024
  gemm_nt<false, false, true, true, true><<<dim3(4, MP / 128), 256, 0, stream>>>(
      h1, w2t, mlp_b2, out_hsem, 512, NGO, 512, gocat, 1024, 0, 1024);

  // --- structure branch ---
  // spmm1: ax = A @ GO16   (reassociated: spmm before dense gc1 GEMM)
  spmm_csr_kernel<false><<<NGO, 256, 0, stream>>>(
      row_start, csr_col, csr_val, (const unsigned*)GO16,
      (unsigned*)ax16, 256, 0, nullptr, nullptr);
  // G3: x = relu(ax @ gc1_w + gc1_b)  [MP,1024] K=512
  gemm_nt<true, false, true, false, true><<<dim3(8, MP / 128), 256, 0, stream>>>(
      ax16, gc1t, gc1_b, nullptr, 0, 0, 0, x16, 1024, 0, 512);
  // G4: xw = x @ gc2_w   [MP,512] K=1024 (bias+relu after spmm2)
  gemm_nt<false, false, false, false, true><<<dim3(4, MP / 128), 256, 0, stream>>>(
      x16, gc2t, nullptr, nullptr, 0, 0, 0, xw16, 512, 0, 1024);
  // spmm2: h_str = relu(A @ xw + gc2_b) -> f32 d_out + bf16 gocat[:,512:1024]
  spmm_csr_kernel<true><<<NGO, 256, 0, stream>>>(
      row_start, csr_col, csr_val, (const unsigned*)xw16,
      (unsigned*)gocat, 512, 256, out_hstr, gc2_b);

  // --- sequence branch ---
  // G5: s1 = relu(seq16 @ se_w1 + se_b1)  [4096,1024] K=1280
  gemm_nt<true, false, true, false, true><<<dim3(8, 32), 256, 0, stream>>>(
      seq16, se1t, se_b1, nullptr, 0, 0, 0, s1b, 1024, 0, 1280);
  // G6: seq_out = s1 @ se_w2 + se_b2   [4096,1024] K=1024
  gemm_nt<false, false, true, false, true><<<dim3(8, 32), 256, 0, stream>>>(
      s1b, se2t, se_b2, nullptr, 0, 0, 0, so16, 1024, 0, 1024);

  // --- prediction: sigmoid(seq_out @ gocat^T)  M=4096, N=40064(pad), K=1024 ---
  gemm_nt<false, true, false, true, false><<<dim3(MP / 128, 32), 256, 0, stream>>>(
      so16, gocat, nullptr, out_pred, NGO, 4096, NGO, nullptr, 0, 0, 1024);
}